// Round 1
// 845.676 us; speedup vs baseline: 1.0482x; 1.0482x over previous
//
#include <hip/hip_runtime.h>

// BioRNN: T=1000, B=4096, H=50, IN=8, OUT=6, fp32.
//   r   = relu(h)
//   y_t = r @ W_out^T + b_out          (r from PRE-update h)
//   h  += DT * (-h + x @ W_in^T + r @ W_rec^T + bias)
//
// Restructure vs previous version: ONE WAVE PER BATCH ELEMENT, one row per
// lane (lane 0..49 hidden rows, 50..55 output rows, 56..63 dummy zeros).
// The r-exchange is wave-internal: ds_write_b32 + s_waitcnt lgkmcnt(0) +
// 13 broadcast ds_read_b128. NO __syncthreads anywhere -> no barrier drain,
// no inter-wave coupling. Single LDS buffer is race-free because step t+1's
// ds_write data (r = relu(h_new)) is register-RAW-dependent on every FMA of
// step t, which depends on all 13 ds_read results.
// One weight row per lane (52 regs) instead of two (104 -> spilled at
// VGPR_Count=92 before): fits VGPRs, 4 waves/SIMD.
// Per-lane accumulation order kept bit-identical to the previous passing
// kernel: acc = bias -> k=0..51 in float4 order -> x i=0..7 ->
// h += DT*(acc - h).

#define T_STEPS 1000
#define BATCH   4096
#define INSZ    8
#define H       50
#define OUTSZ   6
#define DT      0.1f
#define ROWS    56         // 50 hidden + 6 output projections
#define KP      52         // padded dot length (13 * float4; k=50,51 weight=0)
#define WPB     4          // waves (= batch elements) per block

__global__ __launch_bounds__(256, 4)
void biornn_kernel(const float* __restrict__ xg,   // (T, B, INSZ)
                   const float* __restrict__ Wi,   // (H, INSZ)
                   const float* __restrict__ Wr,   // (H, H)
                   const float* __restrict__ bs,   // (H)
                   const float* __restrict__ Wo,   // (OUTSZ, H)
                   const float* __restrict__ bo,   // (OUTSZ)
                   float* __restrict__ out)        // (T, B, OUTSZ)
{
    // per-wave r buffer; 64 floats/wave. Writes stride-1 (conflict-free),
    // reads are same-address broadcast (conflict-free).
    __shared__ __align__(16) float r_lds[WPB][64];

    const int tid  = threadIdx.x;
    const int w    = tid >> 6;            // wave in block = batch slot
    const int lane = tid & 63;            // row index this lane owns
    const int b_glob = blockIdx.x * WPB + w;

    const bool hrow = (lane < H);
    const bool yrow = (lane >= H) && (lane < ROWS);

    // ---- loop-invariant weights into registers (one row per lane) ----
    float wr[KP], wi[INSZ];
    float bias = 0.f;
#pragma unroll
    for (int k = 0; k < KP; ++k) wr[k] = 0.f;
#pragma unroll
    for (int i = 0; i < INSZ; ++i) wi[i] = 0.f;

    if (hrow) {
#pragma unroll
        for (int k = 0; k < H; ++k) wr[k] = Wr[lane * H + k];
#pragma unroll
        for (int i = 0; i < INSZ; ++i) wi[i] = Wi[lane * INSZ + i];
        bias = bs[lane];
    } else if (yrow) {
        const int o = lane - H;
#pragma unroll
        for (int k = 0; k < H; ++k) wr[k] = Wo[o * H + k];
        bias = bo[o];
    }
    // lanes 56..63: all-zero weights, bias 0 -> h stays 0, never stored.

    // ---- per-lane state ----
    float h = 0.f;

    // x[t] for this wave's batch element: uniform 32B, held per-lane in regs,
    // prefetched one step ahead (vector loads -> vmcnt, decoupled from lgkm).
    const float* xp = xg + (size_t)b_glob * INSZ;
    float xv[INSZ];
#pragma unroll
    for (int i = 0; i < INSZ; i += 4) {
        float4 t4 = *(const float4*)(xp + i);
        xv[i] = t4.x; xv[i + 1] = t4.y; xv[i + 2] = t4.z; xv[i + 3] = t4.w;
    }
    xp += (size_t)BATCH * INSZ;

    float* outp = out + (size_t)b_glob * OUTSZ + (yrow ? (lane - H) : 0);

    for (int t = 0; t < T_STEPS; ++t) {
        // publish r = relu(h). Lanes 50..55 publish finite garbage into
        // slots 50..55; only slots 50,51 are ever read and their weights
        // are 0 (fma(g, 0, acc) == acc exactly, g finite).
        const float r = fmaxf(h, 0.f);
        r_lds[w][lane] = r;
        // wave-internal visibility: wait own wave's ds_write (all 64 lanes).
        asm volatile("s_waitcnt lgkmcnt(0)" ::: "memory");

        float acc = bias;
#pragma unroll
        for (int kc = 0; kc < KP / 4; ++kc) {
            const float4 rv = *(const float4*)&r_lds[w][4 * kc];
            acc = fmaf(rv.x, wr[4 * kc + 0], acc);
            acc = fmaf(rv.y, wr[4 * kc + 1], acc);
            acc = fmaf(rv.z, wr[4 * kc + 2], acc);
            acc = fmaf(rv.w, wr[4 * kc + 3], acc);
        }
#pragma unroll
        for (int i = 0; i < INSZ; ++i)
            acc = fmaf(xv[i], wi[i], acc);

        // prefetch x[t+1] (consumed next iteration; vmcnt wait lands there)
        if (t + 1 < T_STEPS) {
#pragma unroll
            for (int i = 0; i < INSZ; i += 4) {
                float4 t4 = *(const float4*)(xp + i);
                xv[i] = t4.x; xv[i + 1] = t4.y; xv[i + 2] = t4.z; xv[i + 3] = t4.w;
            }
            xp += (size_t)BATCH * INSZ;
        }

        // h <- h + DT*(acc - h). Harmless on y/dummy rows (h unused there).
        h += DT * (acc - h);

        // output rows: y_t = acc (b_out folded into bias init)
        if (yrow) outp[(size_t)t * (BATCH * OUTSZ)] = acc;
    }
}

extern "C" void kernel_launch(void* const* d_in, const int* in_sizes, int n_in,
                              void* d_out, int out_size, void* d_ws, size_t ws_size,
                              hipStream_t stream)
{
    const float* xg = (const float*)d_in[0];  // input_seq (1000,4096,8)
    const float* Wi = (const float*)d_in[1];  // W_in (50,8)
    const float* Wr = (const float*)d_in[2];  // W_rec (50,50)
    const float* bs = (const float*)d_in[3];  // bias (50)
    const float* Wo = (const float*)d_in[4];  // W_out_w (6,50)
    const float* bo = (const float*)d_in[5];  // W_out_b (6)
    float* outp = (float*)d_out;              // (1000,4096,6)

    dim3 grid(BATCH / WPB);   // 1024 blocks
    dim3 block(256);          // 4 independent waves per block
    hipLaunchKernelGGL(biornn_kernel, grid, block, 0, stream,
                       xg, Wi, Wr, bs, Wo, bo, outp);
}